// Round 7
// baseline (216.840 us; speedup 1.0000x reference)
//
#include <hip/hip_runtime.h>
#include <math.h>

#define B 256
#define S 50
#define D 32
#define V 10000
#define VPAD 10240
#define KK 16
#define HH 64
#define LL 2
#define UU 32
#define TT 30          // trigger_seq_length
#define NROWS (B*S)    // 12800
#define NORMC 0.01f
#define NSLICE 16
#define SLICE_V 640    // VPAD / NSLICE
#define NTILES 40      // SLICE_V / 16

typedef __attribute__((ext_vector_type(8))) short bf16x8;
typedef __attribute__((ext_vector_type(4))) float f32x4;

__device__ __forceinline__ float sigmoidf_(float x) { return 1.0f / (1.0f + expf(-x)); }

__device__ __forceinline__ unsigned short f2bf(float x) {
    union { float f; unsigned int u; } a; a.f = x;
    unsigned int u = a.u;
    return (unsigned short)((u + 0x7FFFu + ((u >> 16) & 1u)) >> 16);  // RNE, inputs finite
}
__device__ __forceinline__ float bf2f(unsigned short h) {
    union { unsigned int u; float f; } a; a.u = ((unsigned int)h) << 16; return a.f;
}

// ---------------- prep: split embd fp32 -> (hi,lo) bf16, pad to VPAD (zeros, tn=+inf);
// tnorm; zero loss + ticket. (Q is split in-register inside k_vq now.)
__global__ __launch_bounds__(256) void k_prep(const float* __restrict__ embd,
                                              unsigned short* __restrict__ Eh, unsigned short* __restrict__ El,
                                              float* __restrict__ tn, float* __restrict__ loss_sum,
                                              unsigned int* __restrict__ cnt) {
    int gid = blockIdx.x * 256 + threadIdx.x;
    if (gid == 0) loss_sum[0] = 0.f;
    if (gid == 1) cnt[0] = 0u;
    if (gid >= VPAD * 4) return;
    int item = gid >> 2, qd = gid & 3;
    unsigned short* dh = Eh + (size_t)item * D + qd * 8;
    unsigned short* dl = El + (size_t)item * D + qd * 8;
    if (item >= V) {
        unsigned short z[8] = {0, 0, 0, 0, 0, 0, 0, 0};
        *(uint4*)dh = *(const uint4*)z;
        *(uint4*)dl = *(const uint4*)z;
        if (qd == 0) tn[item] = INFINITY;
        return;
    }
    const float* src = embd + (size_t)item * D + qd * 8;
    float4 x0 = *(const float4*)(src);
    float4 x1 = *(const float4*)(src + 4);
    float xs[8] = {x0.x, x0.y, x0.z, x0.w, x1.x, x1.y, x1.z, x1.w};
    unsigned short hv[8], lv[8];
    float ss = 0.f;
#pragma unroll
    for (int i = 0; i < 8; i++) {
        float x = xs[i];
        ss = fmaf(x, x, ss);
        unsigned short h = f2bf(x);
        hv[i] = h;
        lv[i] = f2bf(x - bf2f(h));
    }
    *(uint4*)dh = *(const uint4*)hv;
    *(uint4*)dl = *(const uint4*)lv;
    ss += __shfl_xor(ss, 1);
    ss += __shfl_xor(ss, 2);
    if (qd == 0) tn[item] = 0.5f * ss;
}

// ---------------- VQ argmin v3: barrier-free, LDS-free, stream-B-from-L2 ----------------
// 3200 independent waves (800 blocks x 4): wave = (rowchunk rc 0..199, slice 0..15).
// Wave pins 4 rowtiles of negated-split Q in registers (read from fp32 z1 directly),
// streams 40 E-code-tiles from L2 (1KB coalesced per tile per buffer), 12 MFMA/tile,
// per-lane running argmin, ONE shuffle-reduce at the end.
__global__ __launch_bounds__(256, 4) void k_vq(const float* __restrict__ z1,
                                               const short* __restrict__ Eh, const short* __restrict__ El,
                                               const float* __restrict__ tn,
                                               float2* __restrict__ pbsv) {
    const int lane = threadIdx.x & 63;
    const int gw = blockIdx.x * 4 + (threadIdx.x >> 6);
    const int rc = gw >> 4, slice = gw & 15;
    const int quad = lane >> 4, c15 = lane & 15;
    // A fragments: rows rc*64 + rt*16 + c15, k = quad*8..+7 ; negate + hi/lo split
    bf16x8 ah[4], al[4];
#pragma unroll
    for (int rt = 0; rt < 4; rt++) {
        const float* qp = z1 + (size_t)(rc * 64 + rt * 16 + c15) * 32 + quad * 8;
        float4 x0 = *(const float4*)qp;
        float4 x1v = *(const float4*)(qp + 4);
        float xs[8] = {x0.x, x0.y, x0.z, x0.w, x1v.x, x1v.y, x1v.z, x1v.w};
        short hv[8], lv[8];
#pragma unroll
        for (int i = 0; i < 8; i++) {
            float x = -xs[i];
            unsigned short h = f2bf(x);
            hv[i] = (short)h;
            lv[i] = (short)f2bf(x - bf2f(h));
        }
        ah[rt] = *(const bf16x8*)hv;
        al[rt] = *(const bf16x8*)lv;
    }
    float best[4][4]; int bv[4][4];
#pragma unroll
    for (int rt = 0; rt < 4; rt++)
#pragma unroll
        for (int e = 0; e < 4; e++) { best[rt][e] = INFINITY; bv[rt][e] = 0x7fffffff; }
    const int vbeg = slice * SLICE_V;
    for (int t = 0; t < NTILES; t++) {
        const int code = vbeg + t * 16 + c15;     // lane's B column = output col
        bf16x8 bh = *(const bf16x8*)(Eh + (size_t)code * 32 + quad * 8);
        bf16x8 bl = *(const bf16x8*)(El + (size_t)code * 32 + quad * 8);
        const float tnv = tn[code];               // pad codes carry +inf
#pragma unroll
        for (int rt = 0; rt < 4; rt++) {
            f32x4 acc = {tnv, tnv, tnv, tnv};
            acc = __builtin_amdgcn_mfma_f32_16x16x32_bf16(ah[rt], bh, acc, 0, 0, 0);
            acc = __builtin_amdgcn_mfma_f32_16x16x32_bf16(al[rt], bh, acc, 0, 0, 0);
            acc = __builtin_amdgcn_mfma_f32_16x16x32_bf16(ah[rt], bl, acc, 0, 0, 0);
#pragma unroll
            for (int e = 0; e < 4; e++) {
                float s = acc[e];                 // ascending t => lowest v kept on ties
                if (s < best[rt][e]) { best[rt][e] = s; bv[rt][e] = code; }
            }
        }
    }
    // reduce across the 16 col-lanes (lane bits 0..3); row = rt*16 + quad*4 + e preserved
#pragma unroll
    for (int m = 1; m <= 8; m <<= 1) {
#pragma unroll
        for (int rt = 0; rt < 4; rt++)
#pragma unroll
            for (int e = 0; e < 4; e++) {
                float os = __shfl_xor(best[rt][e], m);
                int   ov = __shfl_xor(bv[rt][e], m);
                if (os < best[rt][e] || (os == best[rt][e] && ov < bv[rt][e])) {
                    best[rt][e] = os; bv[rt][e] = ov;
                }
            }
    }
    if (c15 == 0) {
#pragma unroll
        for (int rt = 0; rt < 4; rt++)
#pragma unroll
            for (int e = 0; e < 4; e++) {
                const int row = rc * 64 + rt * 16 + quad * 4 + e;
                float2 p; p.x = best[rt][e]; p.y = __int_as_float(bv[rt][e]);
                pbsv[(size_t)row * NSLICE + slice] = p;
            }
    }
}

// ---------------- fused: merge + gather + loss + decoder + 2xGRU + MLPs + wgen + apply ----
// One block per sample (256 blocks x 256 thr). Recurrence runs barrier-free in wave 0.
__global__ __launch_bounds__(256) void k_fused(
        const float* __restrict__ x1, const float* __restrict__ z2,
        const float* __restrict__ embd, const float2* __restrict__ pbsv,
        const float* __restrict__ dw1, const float* __restrict__ db1,
        const float* __restrict__ dw2, const float* __restrict__ db2,
        const float* __restrict__ i_wih, const float* __restrict__ i_whh,
        const float* __restrict__ i_bih, const float* __restrict__ i_bhh,
        const float* __restrict__ c_wih, const float* __restrict__ c_whh,
        const float* __restrict__ c_bih, const float* __restrict__ c_bhh,
        const float* __restrict__ im_w1, const float* __restrict__ im_b1,
        const float* __restrict__ im_w2, const float* __restrict__ im_b2,
        const float* __restrict__ cm_w1, const float* __restrict__ cm_b1,
        const float* __restrict__ cm_w2, const float* __restrict__ cm_b2,
        const float* __restrict__ hw1, const float* __restrict__ hb1,
        const float* __restrict__ hw2, const float* __restrict__ hb2,
        const float* __restrict__ lin_w, const float* __restrict__ lin_b,
        const float* __restrict__ lout_w, const float* __restrict__ lout_b,
        float* __restrict__ loss_sum, unsigned int* __restrict__ cnt,
        float* __restrict__ out) {
    __shared__ float zeL[50][33];                    // 6.6 KB
    __shared__ float dw1L[2048], dw2L[2048];         // 16 KB
    __shared__ float db1L[64], db2L[32];
    __shared__ __attribute__((aligned(16))) float xsi[TT + 1][32];   // decoder out = GRU-i input
    __shared__ float gii[TT + 1][96], gic[TT + 1][96];               // 23.8 KB
    __shared__ float aL[TT + 1][65];                 // 8.1 KB
    __shared__ float hI[32], hC[32];
    __shared__ float afL[2][32];
    __shared__ float z1fL[32], z2fL[32];
    __shared__ float wW[512];
    __shared__ float t1s[16], t2s[16], ocs[32];
    __shared__ int   vidL[50];
    __shared__ float lossRed[4];
    const int tid = threadIdx.x;
    const int b = blockIdx.x;
    const float* z2b = z2 + (size_t)b * (S * D);

    // P0: stage decoder weights; merge VQ slice partials
    for (int p = tid; p < 2048; p += 256) { dw1L[p] = dw1[p]; dw2L[p] = dw2[p]; }
    if (tid < 64) db1L[tid] = db1[tid];
    if (tid >= 64 && tid < 96) db2L[tid - 64] = db2[tid - 64];
    if (tid < 50) {
        const float2* pp = pbsv + (size_t)(b * S + tid) * NSLICE;
        float bs = INFINITY; int bv = 0x7fffffff;
#pragma unroll
        for (int j = 0; j < NSLICE; j++) {
            float2 p = pp[j];
            int v = __float_as_int(p.y);
            if (p.x < bs) { bs = p.x; bv = v; }   // ascending slice => lowest v on ties
        }
        vidL[tid] = bv;
    }
    __syncthreads();
    // P1: fetch z_emb rows
    {
        const int q = tid & 7;
#pragma unroll
        for (int it = 0; it < 2; it++) {
            int s = it * 32 + (tid >> 3);
            if (s < 50) {
                float4 e4 = *(const float4*)(embd + (size_t)vidL[s] * D + q * 4);
                zeL[s][q * 4 + 0] = e4.x; zeL[s][q * 4 + 1] = e4.y;
                zeL[s][q * 4 + 2] = e4.z; zeL[s][q * 4 + 3] = e4.w;
            }
        }
    }
    __syncthreads();
    // P2: loss partial + decoder phase A
    {
        const int q = tid & 7;
        float ls = 0.f;
#pragma unroll
        for (int it = 0; it < 2; it++) {
            int s = it * 32 + (tid >> 3);
            if (s < 50) {
                float4 x4 = *(const float4*)(z2b + s * D + q * 4);
                float d0 = x4.x - zeL[s][q * 4 + 0], d1 = x4.y - zeL[s][q * 4 + 1];
                float d2 = x4.z - zeL[s][q * 4 + 2], d3 = x4.w - zeL[s][q * 4 + 3];
                ls += d0 * d0 + d1 * d1 + d2 * d2 + d3 * d3;
            }
        }
#pragma unroll
        for (int off = 32; off > 0; off >>= 1) ls += __shfl_down(ls, off);
        if ((tid & 63) == 0) lossRed[tid >> 6] = ls;
        const int s = tid >> 3;
        if (s <= TT) {
#pragma unroll
            for (int j = 0; j < 8; j++) {
                int h = q * 8 + j;
                float a0 = db1L[h], a1 = 0.f, a2 = 0.f, a3 = 0.f;
#pragma unroll
                for (int d = 0; d < 32; d += 4) {
                    a0 = fmaf(zeL[s][d + 0], dw1L[(d + 0) * 64 + h], a0);
                    a1 = fmaf(zeL[s][d + 1], dw1L[(d + 1) * 64 + h], a1);
                    a2 = fmaf(zeL[s][d + 2], dw1L[(d + 2) * 64 + h], a2);
                    a3 = fmaf(zeL[s][d + 3], dw1L[(d + 3) * 64 + h], a3);
                }
                float a = (a0 + a1) + (a2 + a3);
                aL[s][h] = (a >= 0.f) ? a : 0.1f * a;
            }
        }
    }
    __syncthreads();
    // P3: decoder phase B -> xsi ; block loss atomic
    if (tid == 0) atomicAdd(loss_sum, lossRed[0] + lossRed[1] + lossRed[2] + lossRed[3]);
    {
        const int s = tid >> 3, q = tid & 7;
        if (s <= TT) {
            float zr[4];
#pragma unroll
            for (int dd = 0; dd < 4; dd++) zr[dd] = db2L[q * 4 + dd];
            for (int h = 0; h < 64; h++) {
                float av = aL[s][h];
#pragma unroll
                for (int dd = 0; dd < 4; dd++) zr[dd] = fmaf(av, dw2L[h * 32 + q * 4 + dd], zr[dd]);
            }
            float4 o4 = make_float4(zr[0], zr[1], zr[2], zr[3]);
            *(float4*)&xsi[s][q * 4] = o4;
        }
    }
    __syncthreads();
    // P4: gi precompute. waves 0-1 lanes 0..95 -> GRU-i; waves 2-3 lanes 128..223 -> GRU-c.
    {
        const bool actG = (tid < 96) || (tid >= 128 && tid < 224);
        const int gru = (tid >= 128) ? 1 : 0;
        const int e = gru ? (tid - 128) : tid;
        if (actG) {
            float wihRow[32];
            const float* wg = gru ? c_wih : i_wih;
#pragma unroll
            for (int d = 0; d < 32; d++) wihRow[d] = wg[e * 32 + d];
            const float bi = (gru ? c_bih : i_bih)[e];
            float* giP = gru ? &gic[0][0] : &gii[0][0];
            for (int s = 0; s <= TT; s++) {
                const float4* xp = gru ? (const float4*)(z2b + s * D)
                                       : (const float4*)&xsi[s][0];
                float g0 = bi, g1 = 0.f, g2a = 0.f, g3 = 0.f;
#pragma unroll
                for (int k = 0; k < 8; k++) {
                    float4 xv = xp[k];
                    float* acc = (k & 3) == 0 ? &g0 : ((k & 3) == 1 ? &g1 : ((k & 3) == 2 ? &g2a : &g3));
                    float a = *acc;
                    a = fmaf(xv.x, wihRow[4 * k + 0], a);
                    a = fmaf(xv.y, wihRow[4 * k + 1], a);
                    a = fmaf(xv.z, wihRow[4 * k + 2], a);
                    a = fmaf(xv.w, wihRow[4 * k + 3], a);
                    *acc = a;
                }
                giP[s * 96 + e] = (g0 + g1) + (g2a + g3);
            }
        }
    }
    __syncthreads();
    // P5: dual-GRU recurrence, wave 0 only, barrier-free (h in registers, shfl broadcast)
    if (tid < 64) {
        const int l = tid & 31;
        const int g2 = tid >> 5;                 // 0: GRU-i, 1: GRU-c
        const float* wg = g2 ? c_whh : i_whh;
        float wR[32], wZ[32], wN[32];
#pragma unroll
        for (int d = 0; d < 32; d++) {
            wR[d] = wg[l * 32 + d];
            wZ[d] = wg[(l + 32) * 32 + d];
            wN[d] = wg[(l + 64) * 32 + d];
        }
        const float* bg = g2 ? c_bhh : i_bhh;
        const float bR = bg[l], bZ = bg[l + 32], bN = bg[l + 64];
        const float* giBase = g2 ? &gic[0][0] : &gii[0][0];
        const int src0 = g2 ? 32 : 0;
        float hreg = 0.f;
        for (int t = 0; t <= TT; t++) {
            float gr = bR, gz = bZ, gn = bN;
#pragma unroll
            for (int d = 0; d < 32; d++) {
                float hd = __shfl(hreg, src0 + d, 64);
                gr = fmaf(hd, wR[d], gr);
                gz = fmaf(hd, wZ[d], gz);
                gn = fmaf(hd, wN[d], gn);
            }
            float rr = sigmoidf_(giBase[t * 96 + l] + gr);
            float zz = sigmoidf_(giBase[t * 96 + l + 32] + gz);
            float nn = tanhf(giBase[t * 96 + l + 64] + rr * gn);
            hreg = (1.f - zz) * nn + zz * hreg;
        }
        (g2 ? hC : hI)[l] = hreg;
    }
    __syncthreads();
    // P6: output MLPs. lanes 0..31 -> i-path, 128..159 -> c-path
    {
        const bool actM = (tid < 32) || (tid >= 128 && tid < 160);
        const int g2 = (tid >= 128) ? 1 : 0;
        const int l = tid & 31;
        if (actM) {
            const float* w1 = g2 ? cm_w1 : im_w1;
            const float* b1 = g2 ? cm_b1 : im_b1;
            const float* hP = g2 ? hC : hI;
            float a = b1[l];
#pragma unroll
            for (int d = 0; d < 32; d++) a = fmaf(hP[d], w1[d * 32 + l], a);
            afL[g2][l] = tanhf(a);
        }
        __syncthreads();
        if (actM) {
            const float* w2 = g2 ? cm_w2 : im_w2;
            const float* b2 = g2 ? cm_b2 : im_b2;
            float o = b2[l];
#pragma unroll
            for (int d = 0; d < 32; d++) o = fmaf(afL[g2][d], w2[d * 32 + l], o);
            (g2 ? z2fL : z1fL)[l] = o;
        }
        if (tid < 32) ocs[tid] = x1[b * 32 + tid];
    }
    __syncthreads();
    // P7: wgen  w[ly][kk] = clip(z1f.hw1) + z2f.hw2
    {
        const int kk = tid;
#pragma unroll
        for (int ly = 0; ly < LL; ly++) {
            float a = hb1[ly * 256 + kk], c = hb2[ly * 256 + kk];
            const float* h1 = hw1 + ly * 8192 + kk;
            const float* h2 = hw2 + ly * 8192 + kk;
#pragma unroll
            for (int d = 0; d < 32; d++) {
                a = fmaf(z1fL[d], h1[d * 256], a);
                c = fmaf(z2fL[d], h2[d * 256], c);
            }
            a = fminf(fmaxf(a, -NORMC), NORMC);
            wW[ly * 256 + kk] = a + c;
        }
    }
    __syncthreads();
    // P8: apply
#pragma unroll
    for (int i = 0; i < LL; i++) {
        if (tid < 16) {
            float a = lin_b[i * 16 + tid];
#pragma unroll
            for (int u = 0; u < 32; u++) a = fmaf(ocs[u], lin_w[i * 512 + u * 16 + tid], a);
            t1s[tid] = a;
        }
        __syncthreads();
        if (tid < 16) {
            float a = 0.f;
#pragma unroll
            for (int k = 0; k < 16; k++) a = fmaf(t1s[k], wW[i * 256 + k * 16 + tid], a);
            t2s[tid] = a;
        }
        __syncthreads();
        if (tid < 32) {
            float a = lout_b[i * 32 + tid];
#pragma unroll
            for (int k = 0; k < 16; k++) a = fmaf(t2s[k], lout_w[i * 512 + k * 32 + tid], a);
            ocs[tid] = a;
        }
        __syncthreads();
    }
    if (tid < 32) out[(size_t)b * 32 + tid] = ocs[tid];
    // P9: loss finalize via ticket
    if (tid == 0) {
        __threadfence();
        unsigned int old = atomicAdd(cnt, 1u);
        if (old == B - 1) {
            float tot = atomicAdd(loss_sum, 0.0f);
            out[B * UU] = tot * (1.0f / (float)(B * S * D));
        }
    }
}

extern "C" void kernel_launch(void* const* d_in, const int* in_sizes, int n_in,
                              void* d_out, int out_size, void* d_ws, size_t ws_size,
                              hipStream_t stream) {
    const float* x1     = (const float*)d_in[0];
    const float* z1     = (const float*)d_in[1];
    const float* z2     = (const float*)d_in[3];
    const float* embd   = (const float*)d_in[4];
    const float* dec_w1 = (const float*)d_in[5];
    const float* dec_b1 = (const float*)d_in[6];
    const float* dec_w2 = (const float*)d_in[7];
    const float* dec_b2 = (const float*)d_in[8];
    const float* i_wih  = (const float*)d_in[9];
    const float* i_whh  = (const float*)d_in[10];
    const float* i_bih  = (const float*)d_in[11];
    const float* i_bhh  = (const float*)d_in[12];
    const float* c_wih  = (const float*)d_in[13];
    const float* c_whh  = (const float*)d_in[14];
    const float* c_bih  = (const float*)d_in[15];
    const float* c_bhh  = (const float*)d_in[16];
    const float* im_w1  = (const float*)d_in[17];
    const float* im_b1  = (const float*)d_in[18];
    const float* im_w2  = (const float*)d_in[19];
    const float* im_b2  = (const float*)d_in[20];
    const float* cm_w1  = (const float*)d_in[21];
    const float* cm_b1  = (const float*)d_in[22];
    const float* cm_w2  = (const float*)d_in[23];
    const float* cm_b2  = (const float*)d_in[24];
    const float* hw1    = (const float*)d_in[25];
    const float* hb1    = (const float*)d_in[26];
    const float* hw2    = (const float*)d_in[27];
    const float* hb2    = (const float*)d_in[28];
    const float* lin_w  = (const float*)d_in[29];
    const float* lin_b  = (const float*)d_in[30];
    const float* lout_w = (const float*)d_in[31];
    const float* lout_b = (const float*)d_in[32];

    // workspace layout (floats)
    float* wsf      = (float*)d_ws;
    float* loss_sum = wsf;                        // [0]
    unsigned int* cnt = (unsigned int*)(wsf + 1); // [1]
    float* tn       = wsf + 64;                   // VPAD -> 10304
    float2* pbsv    = (float2*)(wsf + 10304);     // NROWS*NSLICE float2 = 409600 f -> 419904
    unsigned short* Eh = (unsigned short*)(wsf + 419904);  // VPAD*32 shorts = 163840 f -> 583744
    unsigned short* El = (unsigned short*)(wsf + 583744);  // -> 747584  (~3.0 MB)

    k_prep<<<(VPAD * 4 + 255) / 256, 256, 0, stream>>>(embd, Eh, El, tn, loss_sum, cnt);
    k_vq<<<(NROWS / 64) * NSLICE / 4, 256, 0, stream>>>(z1, (const short*)Eh, (const short*)El,
                                                        tn, pbsv);
    k_fused<<<B, 256, 0, stream>>>(x1, z2, embd, pbsv,
                                   dec_w1, dec_b1, dec_w2, dec_b2,
                                   i_wih, i_whh, i_bih, i_bhh,
                                   c_wih, c_whh, c_bih, c_bhh,
                                   im_w1, im_b1, im_w2, im_b2,
                                   cm_w1, cm_b1, cm_w2, cm_b2,
                                   hw1, hb1, hw2, hb2,
                                   lin_w, lin_b, lout_w, lout_b,
                                   loss_sum, cnt, (float*)d_out);
}